// Round 13
// baseline (83.514 us; speedup 1.0000x reference)
//
#include <hip/hip_runtime.h>
#include <math.h>

#define BB 2
#define LL 2048
#define MM 1024
#define DD 16
#define RR 64
#define NN 96
#define BLROWS (BB*LL)          // 4096
#define NCH 64                  // chunks
#define CLEN (LL/NCH)           // 32

#define LOG2E 1.44269504088896340736f

// workspace layout (float offsets). dt region holds bf16 (ushort).
#define OFF_XP    0
#define OFF_DT    (OFF_XP + BLROWS*NN)            // 393216
#define OFF_A2    (OFF_DT + BLROWS*MM/2)          // 2490368
#define OFF_HEND  (OFF_A2 + MM*DD)                // 2506752
#define OFF_DTSUM (OFF_HEND + NCH*BB*MM*DD)       // 4603904
// total = OFF_DTSUM + NCH*BB*MM = 4735232 floats = 18.9 MB

typedef __attribute__((ext_vector_type(8))) short bf16x8;
typedef __attribute__((ext_vector_type(4))) float f32x4;
typedef __attribute__((ext_vector_type(4))) unsigned short u16x4;

union BF8 { bf16x8 v; unsigned u[4]; uint4 q; };

// packed f32x2 -> bf16x2 (RNE): dst = {hi=bf16(b), lo=bf16(a)}
__device__ __forceinline__ unsigned cvtpk(float a, float b) {
  unsigned r;
  asm("v_cvt_pk_bf16_f32 %0, %1, %2" : "=v"(r) : "v"(a), "v"(b));
  return r;
}

// bare v_exp_f32: computes 2^x (operand must be pre-scaled by log2e)
__device__ __forceinline__ float vexp2(float x) {
  float r;
  asm("v_exp_f32 %0, %1" : "=v"(r) : "v"(x));
  return r;
}

// fast softplus: log(1+e^v) via native v_exp/v_log
__device__ __forceinline__ float softplusf(float v) {
  return v > 20.f ? v : __logf(1.f + __expf(v));
}

// f32 -> bf16 round-to-nearest-even (scalar)
__device__ __forceinline__ short f2bf(float f) {
  union { float f; unsigned u; } v; v.f = f;
  unsigned r = v.u + 0x7FFFu + ((v.u >> 16) & 1u);
  return (short)(r >> 16);
}

// cross-lane xor-1 via DPP quad_perm (VALU pipe)
__device__ __forceinline__ float dpp_xor1(float v) {
  int i = __builtin_amdgcn_mov_dpp(__float_as_int(v), 0xB1, 0xF, 0xF, true);
  return __int_as_float(i);
}

// ---------------- xp = x @ W^T (4096 x 96, K=1024) via bf16 MFMA ----------------
// blocks [0,768): GEMM, one wave per 16-row x 32-col tile (2 n-tiles, A loaded once).
// blocks [768,1024): A2 = -exp(A_log)^T * log2e prep (16384 elems).
#define XP_GEMM_BLOCKS ((BLROWS/16)*3)   // 768
__global__ __launch_bounds__(64) void k_xp(const float* __restrict__ x,
                                           const float* __restrict__ W,
                                           const float* __restrict__ A_log,
                                           float* __restrict__ ws) {
  if (blockIdx.x >= XP_GEMM_BLOCKS) {
    int idx = (blockIdx.x - XP_GEMM_BLOCKS) * 64 + threadIdx.x;
    int m = idx >> 4, d = idx & 15;
    ws[OFF_A2 + idx] = -__expf(A_log[d * MM + m]) * LOG2E;
    return;
  }
  float* xp = ws + OFF_XP;
  int lane = threadIdx.x;
  int rt = blockIdx.x / 3, np = blockIdx.x % 3;
  int lr = lane & 15, lk = lane >> 4;
  const float* xr = x + (size_t)(rt * 16 + lr) * MM + lk * 8;
  const float* wr0 = W + (size_t)(np * 32 + lr) * MM + lk * 8;
  const float* wr1 = W + (size_t)(np * 32 + 16 + lr) * MM + lk * 8;
  f32x4 acc0 = {0.f, 0.f, 0.f, 0.f}, acc1 = {0.f, 0.f, 0.f, 0.f};
#pragma unroll 2
  for (int kk = 0; kk < MM; kk += 32) {
    float4 xa = *(const float4*)(xr + kk);
    float4 xb = *(const float4*)(xr + kk + 4);
    float4 p0 = *(const float4*)(wr0 + kk);
    float4 p1 = *(const float4*)(wr0 + kk + 4);
    float4 q0 = *(const float4*)(wr1 + kk);
    float4 q1 = *(const float4*)(wr1 + kk + 4);
    BF8 a, b0, b1;
    a.u[0] = cvtpk(xa.x, xa.y); a.u[1] = cvtpk(xa.z, xa.w);
    a.u[2] = cvtpk(xb.x, xb.y); a.u[3] = cvtpk(xb.z, xb.w);
    b0.u[0] = cvtpk(p0.x, p0.y); b0.u[1] = cvtpk(p0.z, p0.w);
    b0.u[2] = cvtpk(p1.x, p1.y); b0.u[3] = cvtpk(p1.z, p1.w);
    b1.u[0] = cvtpk(q0.x, q0.y); b1.u[1] = cvtpk(q0.z, q0.w);
    b1.u[2] = cvtpk(q1.x, q1.y); b1.u[3] = cvtpk(q1.z, q1.w);
    acc0 = __builtin_amdgcn_mfma_f32_16x16x32_bf16(a.v, b0.v, acc0, 0, 0, 0);
    acc1 = __builtin_amdgcn_mfma_f32_16x16x32_bf16(a.v, b1.v, acc1, 0, 0, 0);
  }
  int r0 = rt * 16 + lk * 4, c0 = np * 32 + lr;
#pragma unroll
  for (int e = 0; e < 4; ++e) {
    xp[(size_t)(r0 + e) * NN + c0] = acc0[e];
    xp[(size_t)(r0 + e) * NN + c0 + 16] = acc1[e];
  }
}

// ---------------- dt = softplus(xp[:, :64] @ dtW^T + b), bf16 out, via MFMA ----------------
__global__ __launch_bounds__(64) void k_dt(const float* __restrict__ dtW,
                                           const float* __restrict__ dtb,
                                           float* __restrict__ ws) {
  const float* xp = ws + OFF_XP;
  unsigned short* dt16 = (unsigned short*)(ws + OFF_DT);
  int lane = threadIdx.x;
  int rt = blockIdx.x >> 3, mg = blockIdx.x & 7;
  int lr = lane & 15, lk = lane >> 4;
  const float* xr = xp + (size_t)(rt * 16 + lr) * NN + lk * 8;
  BF8 a0, a1;
  {
    float4 xa = *(const float4*)(xr);
    float4 xb = *(const float4*)(xr + 4);
    float4 xc = *(const float4*)(xr + 32);
    float4 xd = *(const float4*)(xr + 36);
    a0.u[0] = cvtpk(xa.x, xa.y); a0.u[1] = cvtpk(xa.z, xa.w);
    a0.u[2] = cvtpk(xb.x, xb.y); a0.u[3] = cvtpk(xb.z, xb.w);
    a1.u[0] = cvtpk(xc.x, xc.y); a1.u[1] = cvtpk(xc.z, xc.w);
    a1.u[2] = cvtpk(xd.x, xd.y); a1.u[3] = cvtpk(xd.z, xd.w);
  }
  int r0 = rt * 16 + lk * 4;
#pragma unroll 2
  for (int mt = 0; mt < 8; ++mt) {
    int mcol = (mg * 8 + mt) * 16 + lr;
    const float* wr = dtW + (size_t)mcol * RR + lk * 8;
    float4 p0 = *(const float4*)(wr);
    float4 p1 = *(const float4*)(wr + 4);
    float4 p2 = *(const float4*)(wr + 32);
    float4 p3 = *(const float4*)(wr + 36);
    BF8 b0, b1;
    b0.u[0] = cvtpk(p0.x, p0.y); b0.u[1] = cvtpk(p0.z, p0.w);
    b0.u[2] = cvtpk(p1.x, p1.y); b0.u[3] = cvtpk(p1.z, p1.w);
    b1.u[0] = cvtpk(p2.x, p2.y); b1.u[1] = cvtpk(p2.z, p2.w);
    b1.u[2] = cvtpk(p3.x, p3.y); b1.u[3] = cvtpk(p3.z, p3.w);
    f32x4 acc = {0.f, 0.f, 0.f, 0.f};
    acc = __builtin_amdgcn_mfma_f32_16x16x32_bf16(a0.v, b0.v, acc, 0, 0, 0);
    acc = __builtin_amdgcn_mfma_f32_16x16x32_bf16(a1.v, b1.v, acc, 0, 0, 0);
    float bv = dtb[mcol];
#pragma unroll
    for (int e = 0; e < 4; ++e)
      dt16[(size_t)(r0 + e) * MM + mcol] = (unsigned short)f2bf(softplusf(acc[e] + bv));
  }
}

// ---------------- scan phase 1: per-chunk h_end and sum(dt) ----------------
// d-split x2: thread = (m, d-half). wg covers 128 m's. grid 8*NCH*BB = 1024, block 256.
// (dt,x) packed as bf16 pair in one u32 LDS word -> 1 ds_read_b32/step.
__global__ __launch_bounds__(256) void k_scan1(const float* __restrict__ x,
                                               float* __restrict__ ws) {
  const float* xp = ws + OFF_XP;
  const float* A2t = ws + OFF_A2;
  float* hend = ws + OFF_HEND;
  float* dtsum = ws + OFF_DTSUM;
  __shared__ __align__(16) unsigned dtxs[CLEN * 128];   // 16KB: hi=bf16(x), lo=bf16(dt)
  __shared__ __align__(16) float bs[CLEN * DD];         // 2KB
  int wg = blockIdx.x;
  int mw = wg & 7, c = (wg >> 3) & (NCH - 1), b = wg >> 9;
  int t = threadIdx.x;
  int ml = t >> 1, dsub = t & 1;
  int m0 = mw * 128, m = m0 + ml;
  int l0 = c * CLEN;
  const unsigned short* dtg = (const unsigned short*)(ws + OFF_DT) + (size_t)(b * LL + l0) * MM + m0;
  const float* xg = x + (size_t)(b * LL + l0) * MM + m0;
#pragma unroll
  for (int i = t; i < CLEN * 32; i += 256) {
    int lo = i >> 5, q = i & 31;
    u16x4 dv = *(const u16x4*)&dtg[(size_t)lo * MM + q * 4];
    float4 xv = *(const float4*)&xg[(size_t)lo * MM + q * 4];
    unsigned xp01 = cvtpk(xv.x, xv.y), xp23 = cvtpk(xv.z, xv.w);
    uint4 o;
    o.x = ((xp01 & 0xffffu) << 16) | (unsigned)dv[0];
    o.y = (xp01 & 0xffff0000u) | (unsigned)dv[1];
    o.z = ((xp23 & 0xffffu) << 16) | (unsigned)dv[2];
    o.w = (xp23 & 0xffff0000u) | (unsigned)dv[3];
    *(uint4*)&dtxs[lo * 128 + q * 4] = o;
  }
#pragma unroll
  for (int i = t; i < CLEN * DD; i += 256) {
    int r = i >> 4, cc = i & 15;
    bs[i] = xp[(size_t)(b * LL + l0 + r) * NN + RR + cc];
  }
  __syncthreads();
  float4 A2a = *(const float4*)&A2t[m * DD + dsub * 8];
  float4 A2b = *(const float4*)&A2t[m * DD + dsub * 8 + 4];
  float h0_ = 0.f, h1_ = 0.f, h2_ = 0.f, h3_ = 0.f;
  float h4_ = 0.f, h5_ = 0.f, h6_ = 0.f, h7_ = 0.f, S = 0.f;
#pragma unroll 4
  for (int lo = 0; lo < CLEN; ++lo) {
    unsigned p = dtxs[lo * 128 + ml];
    float dtv = __uint_as_float(p << 16);
    float xv = __uint_as_float(p & 0xffff0000u);
    float4 B0 = *(const float4*)&bs[lo * DD + dsub * 8];
    float4 B1 = *(const float4*)&bs[lo * DD + dsub * 8 + 4];
    S += dtv;
    float dtx = dtv * xv;
    h0_ = vexp2(dtv * A2a.x) * h0_ + dtx * B0.x;
    h1_ = vexp2(dtv * A2a.y) * h1_ + dtx * B0.y;
    h2_ = vexp2(dtv * A2a.z) * h2_ + dtx * B0.z;
    h3_ = vexp2(dtv * A2a.w) * h3_ + dtx * B0.w;
    h4_ = vexp2(dtv * A2b.x) * h4_ + dtx * B1.x;
    h5_ = vexp2(dtv * A2b.y) * h5_ + dtx * B1.y;
    h6_ = vexp2(dtv * A2b.z) * h6_ + dtx * B1.z;
    h7_ = vexp2(dtv * A2b.w) * h7_ + dtx * B1.w;
  }
  size_t o = ((size_t)((c * BB + b) * MM + m)) * DD + dsub * 8;
  *(float4*)&hend[o] = make_float4(h0_, h1_, h2_, h3_);
  *(float4*)&hend[o + 4] = make_float4(h4_, h5_, h6_, h7_);
  if (dsub == 0) dtsum[(c * BB + b) * MM + m] = S;
}

// ---------------- scan phase 2: scan over chunks (software-pipelined), h0 in place ----------------
__global__ __launch_bounds__(256) void k_scan2(float* __restrict__ ws) {
  int t = blockIdx.x * 256 + threadIdx.x; // 32768 threads
  int d = t & 15, m = (t >> 4) & 1023, b = t >> 14;
  float* hend = ws + OFF_HEND;
  const float* dtsum = ws + OFF_DTSUM;
  float A2 = ws[OFF_A2 + m * DD + d];
  const size_t hstride = (size_t)BB * MM * DD;
  const int sstride = BB * MM;
  size_t o = ((size_t)b * MM + m) * DD + d;
  int si = b * MM + m;
  float h = 0.f;
  float he = hend[o], S = dtsum[si];
  for (int c = 0; c < NCH; ++c) {
    float heN = 0.f, SN = 0.f;
    if (c + 1 < NCH) {
      heN = hend[o + hstride];
      SN = dtsum[si + sstride];
    }
    hend[o] = h;                  // h0 for chunk c
    h = vexp2(A2 * S) * h + he;
    he = heN; S = SN;
    o += hstride; si += sstride;
  }
}

// ---------------- scan phase 3: recompute with h0, emit y * silu(z). d-split x2 ----------------
__global__ __launch_bounds__(256) void k_scan3(const float* __restrict__ x,
                                               const float* __restrict__ z,
                                               const float* __restrict__ Dp,
                                               float* __restrict__ out,
                                               float* __restrict__ ws) {
  const float* xp = ws + OFF_XP;
  const float* A2t = ws + OFF_A2;
  const float* h0w = ws + OFF_HEND;      // phase 2 left h0 here
  __shared__ __align__(16) unsigned dtxs[CLEN * 128];   // 16KB
  __shared__ __align__(16) float zs_[CLEN * 128];       // 16KB
  __shared__ __align__(16) float bs[CLEN * 32];         // 4KB
  int wg = blockIdx.x;
  int mw = wg & 7, c = (wg >> 3) & (NCH - 1), b = wg >> 9;
  int t = threadIdx.x;
  int ml = t >> 1, dsub = t & 1;
  int m0 = mw * 128, m = m0 + ml;
  int l0 = c * CLEN;
  const unsigned short* dtg = (const unsigned short*)(ws + OFF_DT) + (size_t)(b * LL + l0) * MM + m0;
  const float* xg = x + (size_t)(b * LL + l0) * MM + m0;
  const float* zg = z + (size_t)(b * LL + l0) * MM + m0;
#pragma unroll
  for (int i = t; i < CLEN * 32; i += 256) {
    int lo = i >> 5, q = i & 31;
    u16x4 dv = *(const u16x4*)&dtg[(size_t)lo * MM + q * 4];
    float4 xv = *(const float4*)&xg[(size_t)lo * MM + q * 4];
    unsigned xp01 = cvtpk(xv.x, xv.y), xp23 = cvtpk(xv.z, xv.w);
    uint4 o;
    o.x = ((xp01 & 0xffffu) << 16) | (unsigned)dv[0];
    o.y = (xp01 & 0xffff0000u) | (unsigned)dv[1];
    o.z = ((xp23 & 0xffffu) << 16) | (unsigned)dv[2];
    o.w = (xp23 & 0xffff0000u) | (unsigned)dv[3];
    *(uint4*)&dtxs[lo * 128 + q * 4] = o;
    *(float4*)&zs_[lo * 128 + q * 4] = *(const float4*)&zg[(size_t)lo * MM + q * 4];
  }
#pragma unroll
  for (int i = t; i < CLEN * 32; i += 256) {
    int r = i >> 5, cc = i & 31;
    bs[i] = xp[(size_t)(b * LL + l0 + r) * NN + RR + cc];
  }
  __syncthreads();
  float4 A2a = *(const float4*)&A2t[m * DD + dsub * 8];
  float4 A2b = *(const float4*)&A2t[m * DD + dsub * 8 + 4];
  size_t o = ((size_t)((c * BB + b) * MM + m)) * DD + dsub * 8;
  float4 hva = *(const float4*)&h0w[o];
  float4 hvb = *(const float4*)&h0w[o + 4];
  float h0_ = hva.x, h1_ = hva.y, h2_ = hva.z, h3_ = hva.w;
  float h4_ = hvb.x, h5_ = hvb.y, h6_ = hvb.z, h7_ = hvb.w;
  float Dpm = Dp[m];
  size_t idx = ((size_t)(b * LL + l0)) * MM + m;
#pragma unroll 4
  for (int lo = 0; lo < CLEN; ++lo) {
    unsigned p = dtxs[lo * 128 + ml];
    float dtv = __uint_as_float(p << 16);
    float xv = __uint_as_float(p & 0xffff0000u);
    float zv = zs_[lo * 128 + ml];
    float4 B0 = *(const float4*)&bs[lo * 32 + dsub * 8];
    float4 B1 = *(const float4*)&bs[lo * 32 + dsub * 8 + 4];
    float4 C0 = *(const float4*)&bs[lo * 32 + DD + dsub * 8];
    float4 C1 = *(const float4*)&bs[lo * 32 + DD + dsub * 8 + 4];
    float dtx = dtv * xv;
    h0_ = vexp2(dtv * A2a.x) * h0_ + dtx * B0.x;
    h1_ = vexp2(dtv * A2a.y) * h1_ + dtx * B0.y;
    h2_ = vexp2(dtv * A2a.z) * h2_ + dtx * B0.z;
    h3_ = vexp2(dtv * A2a.w) * h3_ + dtx * B0.w;
    h4_ = vexp2(dtv * A2b.x) * h4_ + dtx * B1.x;
    h5_ = vexp2(dtv * A2b.y) * h5_ + dtx * B1.y;
    h6_ = vexp2(dtv * A2b.z) * h6_ + dtx * B1.z;
    h7_ = vexp2(dtv * A2b.w) * h7_ + dtx * B1.w;
    float yp = h0_ * C0.x + h1_ * C0.y + h2_ * C0.z + h3_ * C0.w
             + h4_ * C1.x + h5_ * C1.y + h6_ * C1.z + h7_ * C1.w;
    yp += dpp_xor1(yp);
    float sig = __builtin_amdgcn_rcpf(1.f + vexp2(-LOG2E * zv));
    if (dsub == 0)
      out[idx + (size_t)lo * MM] = (yp + Dpm * xv) * zv * sig;
  }
}

extern "C" void kernel_launch(void* const* d_in, const int* in_sizes, int n_in,
                              void* d_out, int out_size, void* d_ws, size_t ws_size,
                              hipStream_t stream) {
  const float* x = (const float*)d_in[0];
  const float* z = (const float*)d_in[1];
  const float* W = (const float*)d_in[2];
  const float* dtW = (const float*)d_in[3];
  const float* dtb = (const float*)d_in[4];
  const float* A_log = (const float*)d_in[5];
  const float* Dp = (const float*)d_in[6];
  float* out = (float*)d_out;
  float* ws = (float*)d_ws;

  k_xp<<<XP_GEMM_BLOCKS + (MM * DD / 64), 64, 0, stream>>>(x, W, A_log, ws);
  k_dt<<<(BLROWS / 16) * 8, 64, 0, stream>>>(dtW, dtb, ws);
  k_scan1<<<8 * NCH * BB, 256, 0, stream>>>(x, ws);
  k_scan2<<<128, 256, 0, stream>>>(ws);
  k_scan3<<<8 * NCH * BB, 256, 0, stream>>>(x, z, Dp, out, ws);
}

// Round 14
// 82.717 us; speedup vs baseline: 1.0096x; 1.0096x over previous
//
#include <hip/hip_runtime.h>
#include <math.h>

#define BB 2
#define LL 2048
#define MM 1024
#define DD 16
#define RR 64
#define NN 96
#define BLROWS (BB*LL)          // 4096
#define NCH 64                  // chunks
#define CLEN (LL/NCH)           // 32

#define LOG2E 1.44269504088896340736f

// workspace layout (float offsets). dt/WB/DWB regions hold bf16 (ushort).
#define OFF_XP    0
#define OFF_DT    (OFF_XP + BLROWS*NN)            // 393216
#define OFF_A2    (OFF_DT + BLROWS*MM/2)          // 2490368
#define OFF_HEND  (OFF_A2 + MM*DD)                // 2506752
#define OFF_DTSUM (OFF_HEND + NCH*BB*MM*DD)       // 4603904
#define OFF_WB    (OFF_DTSUM + NCH*BB*MM)         // 4734976 (W bf16: 98304 u16)
#define OFF_DWB   (OFF_WB + MM*NN/2)              // 4784128 (dtW bf16: 65536 u16)
// total = OFF_DWB + RR*MM/2 = 4816896 floats = 19.3 MB

typedef __attribute__((ext_vector_type(8))) short bf16x8;
typedef __attribute__((ext_vector_type(4))) float f32x4;
typedef __attribute__((ext_vector_type(2))) float f32x2;
typedef __attribute__((ext_vector_type(4))) unsigned short u16x4;

union BF8 { bf16x8 v; unsigned u[4]; uint4 q; };

// packed f32x2 -> bf16x2 (RNE): dst = {hi=bf16(b), lo=bf16(a)}
__device__ __forceinline__ unsigned cvtpk(float a, float b) {
  unsigned r;
  asm("v_cvt_pk_bf16_f32 %0, %1, %2" : "=v"(r) : "v"(a), "v"(b));
  return r;
}

// bare v_exp_f32: computes 2^x (operand must be pre-scaled by log2e)
__device__ __forceinline__ float vexp2(float x) {
  float r;
  asm("v_exp_f32 %0, %1" : "=v"(r) : "v"(x));
  return r;
}

// packed dual-issue f32 math (VOP3P) — 2 FMA/mul per instruction
__device__ __forceinline__ f32x2 pk_mul(f32x2 a, f32x2 b) {
  f32x2 r;
  asm("v_pk_mul_f32 %0, %1, %2" : "=v"(r) : "v"(a), "v"(b));
  return r;
}
__device__ __forceinline__ f32x2 pk_fma(f32x2 a, f32x2 b, f32x2 c) {
  f32x2 r;
  asm("v_pk_fma_f32 %0, %1, %2, %3" : "=v"(r) : "v"(a), "v"(b), "v"(c));
  return r;
}

// fast softplus: log(1+e^v) via native v_exp/v_log
__device__ __forceinline__ float softplusf(float v) {
  return v > 20.f ? v : __logf(1.f + __expf(v));
}

// f32 -> bf16 round-to-nearest-even (scalar)
__device__ __forceinline__ short f2bf(float f) {
  union { float f; unsigned u; } v; v.f = f;
  unsigned r = v.u + 0x7FFFu + ((v.u >> 16) & 1u);
  return (short)(r >> 16);
}

__device__ __forceinline__ float bf2f(unsigned short u) {
  return __uint_as_float((unsigned)u << 16);
}

// cross-lane xor-1 / xor-2 via DPP quad_perm (VALU pipe, not LDS pipe)
__device__ __forceinline__ float dpp_xor1(float v) {
  int i = __builtin_amdgcn_mov_dpp(__float_as_int(v), 0xB1, 0xF, 0xF, true);
  return __int_as_float(i);
}
__device__ __forceinline__ float dpp_xor2(float v) {
  int i = __builtin_amdgcn_mov_dpp(__float_as_int(v), 0x4E, 0xF, 0xF, true);
  return __int_as_float(i);
}

// ---------------- prep: W->bf16, dtW->bf16, A2 = -exp(A_log)^T * log2e ----------------
__global__ __launch_bounds__(256) void k_prep(const float* __restrict__ W,
                                              const float* __restrict__ dtW,
                                              const float* __restrict__ A_log,
                                              float* __restrict__ ws) {
  int idx = blockIdx.x * 256 + threadIdx.x;
  if (idx < 24576) {
    float4 v = *(const float4*)&W[idx * 4];
    uint2 p; p.x = cvtpk(v.x, v.y); p.y = cvtpk(v.z, v.w);
    *(uint2*)&((unsigned short*)(ws + OFF_WB))[idx * 4] = p;
  } else if (idx < 24576 + 16384) {
    int j = idx - 24576;
    float4 v = *(const float4*)&dtW[j * 4];
    uint2 p; p.x = cvtpk(v.x, v.y); p.y = cvtpk(v.z, v.w);
    *(uint2*)&((unsigned short*)(ws + OFF_DWB))[j * 4] = p;
  } else if (idx < 24576 + 16384 + 16384) {
    int j = idx - 24576 - 16384;
    int m = j >> 4, d = j & 15;
    ws[OFF_A2 + j] = -__expf(A_log[d * MM + m]) * LOG2E;
  }
}

// ---------------- xp = x @ W^T (4096 x 96, K=1024) via bf16 MFMA ----------------
__global__ __launch_bounds__(64) void k_xp(const float* __restrict__ x,
                                           float* __restrict__ ws) {
  float* xp = ws + OFF_XP;
  const unsigned short* wb16 = (const unsigned short*)(ws + OFF_WB);
  int lane = threadIdx.x;
  int rt = blockIdx.x / 3, np = blockIdx.x % 3;
  int lr = lane & 15, lk = lane >> 4;
  const float* xr = x + (size_t)(rt * 16 + lr) * MM + lk * 8;
  const unsigned short* wr0 = wb16 + (size_t)(np * 32 + lr) * MM + lk * 8;
  const unsigned short* wr1 = wb16 + (size_t)(np * 32 + 16 + lr) * MM + lk * 8;
  f32x4 acc0 = {0.f, 0.f, 0.f, 0.f}, acc1 = {0.f, 0.f, 0.f, 0.f};
#pragma unroll 4
  for (int kk = 0; kk < MM; kk += 32) {
    float4 xa = *(const float4*)(xr + kk);
    float4 xb = *(const float4*)(xr + kk + 4);
    BF8 a, b0, b1;
    b0.q = *(const uint4*)(wr0 + kk);
    b1.q = *(const uint4*)(wr1 + kk);
    a.u[0] = cvtpk(xa.x, xa.y); a.u[1] = cvtpk(xa.z, xa.w);
    a.u[2] = cvtpk(xb.x, xb.y); a.u[3] = cvtpk(xb.z, xb.w);
    acc0 = __builtin_amdgcn_mfma_f32_16x16x32_bf16(a.v, b0.v, acc0, 0, 0, 0);
    acc1 = __builtin_amdgcn_mfma_f32_16x16x32_bf16(a.v, b1.v, acc1, 0, 0, 0);
  }
  int r0 = rt * 16 + lk * 4, c0 = np * 32 + lr;
#pragma unroll
  for (int e = 0; e < 4; ++e) {
    xp[(size_t)(r0 + e) * NN + c0] = acc0[e];
    xp[(size_t)(r0 + e) * NN + c0 + 16] = acc1[e];
  }
}

// ---------------- dt = softplus(xp[:, :64] @ dtW^T + b), bf16 out, via MFMA ----------------
__global__ __launch_bounds__(64) void k_dt(const float* __restrict__ dtb,
                                           float* __restrict__ ws) {
  const float* xp = ws + OFF_XP;
  const unsigned short* dwb16 = (const unsigned short*)(ws + OFF_DWB);
  unsigned short* dt16 = (unsigned short*)(ws + OFF_DT);
  int lane = threadIdx.x;
  int rt = blockIdx.x >> 3, mg = blockIdx.x & 7;
  int lr = lane & 15, lk = lane >> 4;
  const float* xr = xp + (size_t)(rt * 16 + lr) * NN + lk * 8;
  BF8 a0, a1;
  {
    float4 xa = *(const float4*)(xr);
    float4 xb = *(const float4*)(xr + 4);
    float4 xc = *(const float4*)(xr + 32);
    float4 xd = *(const float4*)(xr + 36);
    a0.u[0] = cvtpk(xa.x, xa.y); a0.u[1] = cvtpk(xa.z, xa.w);
    a0.u[2] = cvtpk(xb.x, xb.y); a0.u[3] = cvtpk(xb.z, xb.w);
    a1.u[0] = cvtpk(xc.x, xc.y); a1.u[1] = cvtpk(xc.z, xc.w);
    a1.u[2] = cvtpk(xd.x, xd.y); a1.u[3] = cvtpk(xd.z, xd.w);
  }
  int r0 = rt * 16 + lk * 4;
#pragma unroll 2
  for (int mt = 0; mt < 8; ++mt) {
    int mcol = (mg * 8 + mt) * 16 + lr;
    const unsigned short* wr = dwb16 + (size_t)mcol * RR + lk * 8;
    BF8 b0, b1;
    b0.q = *(const uint4*)(wr);
    b1.q = *(const uint4*)(wr + 32);
    f32x4 acc = {0.f, 0.f, 0.f, 0.f};
    acc = __builtin_amdgcn_mfma_f32_16x16x32_bf16(a0.v, b0.v, acc, 0, 0, 0);
    acc = __builtin_amdgcn_mfma_f32_16x16x32_bf16(a1.v, b1.v, acc, 0, 0, 0);
    float bv = dtb[mcol];
#pragma unroll
    for (int e = 0; e < 4; ++e)
      dt16[(size_t)(r0 + e) * MM + mcol] = (unsigned short)f2bf(softplusf(acc[e] + bv));
  }
}

// ---------------- scan phase 1: per-chunk h_end and sum(dt) ----------------
// d-split x4 (R12 structure), packed-f32 inner loop.
__global__ __launch_bounds__(256) void k_scan1(const float* __restrict__ x,
                                               float* __restrict__ ws) {
  const float* xp = ws + OFF_XP;
  const float* A2t = ws + OFF_A2;
  float* hend = ws + OFF_HEND;
  float* dtsum = ws + OFF_DTSUM;
  __shared__ __align__(16) float ds_[CLEN * 64];
  __shared__ __align__(16) float xs_[CLEN * 64];
  __shared__ __align__(16) float bs[CLEN * DD];
  int wg = blockIdx.x;
  int mw = wg & 15, c = (wg >> 4) & (NCH - 1), b = wg >> 10;
  int t = threadIdx.x;
  int ml = t >> 2, dsub = t & 3;
  int m0 = mw * 64, m = m0 + ml;
  int l0 = c * CLEN;
  const unsigned short* dtg = (const unsigned short*)(ws + OFF_DT) + (size_t)(b * LL + l0) * MM + m0;
  const float* xg = x + (size_t)(b * LL + l0) * MM + m0;
#pragma unroll
  for (int i = t; i < CLEN * 16; i += 256) {
    int lo = i >> 4, q = i & 15;
    u16x4 dv = *(const u16x4*)&dtg[(size_t)lo * MM + q * 4];
    *(float4*)&ds_[lo * 64 + q * 4] = make_float4(bf2f(dv[0]), bf2f(dv[1]), bf2f(dv[2]), bf2f(dv[3]));
    *(float4*)&xs_[lo * 64 + q * 4] = *(const float4*)&xg[(size_t)lo * MM + q * 4];
  }
  for (int i = t; i < CLEN * DD; i += 256) {
    int r = i >> 4, cc = i & 15;
    bs[i] = xp[(size_t)(b * LL + l0 + r) * NN + RR + cc];
  }
  __syncthreads();
  float4 A2v = *(const float4*)&A2t[m * DD + dsub * 4];
  f32x2 A01, A23;
  A01.x = A2v.x; A01.y = A2v.y; A23.x = A2v.z; A23.y = A2v.w;
  f32x2 h01 = {0.f, 0.f}, h23 = {0.f, 0.f};
  float S = 0.f;
#pragma unroll 4
  for (int lo = 0; lo < CLEN; ++lo) {
    float dtv = ds_[lo * 64 + ml];
    float xv = xs_[lo * 64 + ml];
    float4 Bv = *(const float4*)&bs[lo * DD + dsub * 4];
    S += dtv;
    float dtx = dtv * xv;
    f32x2 dt2; dt2.x = dtv; dt2.y = dtv;
    f32x2 dtx2; dtx2.x = dtx; dtx2.y = dtx;
    f32x2 e01 = pk_mul(dt2, A01), e23 = pk_mul(dt2, A23);
    e01.x = vexp2(e01.x); e01.y = vexp2(e01.y);
    e23.x = vexp2(e23.x); e23.y = vexp2(e23.y);
    f32x2 B01, B23;
    B01.x = Bv.x; B01.y = Bv.y; B23.x = Bv.z; B23.y = Bv.w;
    h01 = pk_fma(e01, h01, pk_mul(dtx2, B01));
    h23 = pk_fma(e23, h23, pk_mul(dtx2, B23));
  }
  size_t o = ((size_t)((c * BB + b) * MM + m)) * DD + dsub * 4;
  *(float4*)&hend[o] = make_float4(h01.x, h01.y, h23.x, h23.y);
  if (dsub == 0) dtsum[(c * BB + b) * MM + m] = S;
}

// ---------------- scan phase 2: scan over chunks (software-pipelined), h0 in place ----------------
__global__ __launch_bounds__(256) void k_scan2(float* __restrict__ ws) {
  int t = blockIdx.x * 256 + threadIdx.x; // 32768 threads
  int d = t & 15, m = (t >> 4) & 1023, b = t >> 14;
  float* hend = ws + OFF_HEND;
  const float* dtsum = ws + OFF_DTSUM;
  float A2 = ws[OFF_A2 + m * DD + d];
  const size_t hstride = (size_t)BB * MM * DD;
  const int sstride = BB * MM;
  size_t o = ((size_t)b * MM + m) * DD + d;
  int si = b * MM + m;
  float h = 0.f;
  float he = hend[o], S = dtsum[si];
  for (int c = 0; c < NCH; ++c) {
    float heN = 0.f, SN = 0.f;
    if (c + 1 < NCH) {
      heN = hend[o + hstride];
      SN = dtsum[si + sstride];
    }
    hend[o] = h;                  // h0 for chunk c
    h = vexp2(A2 * S) * h + he;
    he = heN; S = SN;
    o += hstride; si += sstride;
  }
}

// ---------------- scan phase 3: recompute with h0, emit y * silu(z). d-split x4, packed ----------------
__global__ __launch_bounds__(256) void k_scan3(const float* __restrict__ x,
                                               const float* __restrict__ z,
                                               const float* __restrict__ Dp,
                                               float* __restrict__ out,
                                               float* __restrict__ ws) {
  const float* xp = ws + OFF_XP;
  const float* A2t = ws + OFF_A2;
  const float* h0w = ws + OFF_HEND;      // phase 2 left h0 here
  __shared__ __align__(16) float ds_[CLEN * 64];
  __shared__ __align__(16) float xs_[CLEN * 64];
  __shared__ __align__(16) float zs_[CLEN * 64];
  __shared__ __align__(16) float bs[CLEN * 32];
  int wg = blockIdx.x;
  int mw = wg & 15, c = (wg >> 4) & (NCH - 1), b = wg >> 10;
  int t = threadIdx.x;
  int ml = t >> 2, dsub = t & 3;
  int m0 = mw * 64, m = m0 + ml;
  int l0 = c * CLEN;
  const unsigned short* dtg = (const unsigned short*)(ws + OFF_DT) + (size_t)(b * LL + l0) * MM + m0;
  const float* xg = x + (size_t)(b * LL + l0) * MM + m0;
  const float* zg = z + (size_t)(b * LL + l0) * MM + m0;
#pragma unroll
  for (int i = t; i < CLEN * 16; i += 256) {
    int lo = i >> 4, q = i & 15;
    u16x4 dv = *(const u16x4*)&dtg[(size_t)lo * MM + q * 4];
    *(float4*)&ds_[lo * 64 + q * 4] = make_float4(bf2f(dv[0]), bf2f(dv[1]), bf2f(dv[2]), bf2f(dv[3]));
    *(float4*)&xs_[lo * 64 + q * 4] = *(const float4*)&xg[(size_t)lo * MM + q * 4];
    *(float4*)&zs_[lo * 64 + q * 4] = *(const float4*)&zg[(size_t)lo * MM + q * 4];
  }
  for (int i = t; i < CLEN * 32; i += 256) {
    int r = i >> 5, cc = i & 31;
    bs[i] = xp[(size_t)(b * LL + l0 + r) * NN + RR + cc];
  }
  __syncthreads();
  float4 A2v = *(const float4*)&A2t[m * DD + dsub * 4];
  f32x2 A01, A23;
  A01.x = A2v.x; A01.y = A2v.y; A23.x = A2v.z; A23.y = A2v.w;
  size_t o = ((size_t)((c * BB + b) * MM + m)) * DD + dsub * 4;
  float4 hv = *(const float4*)&h0w[o];
  f32x2 h01, h23;
  h01.x = hv.x; h01.y = hv.y; h23.x = hv.z; h23.y = hv.w;
  float Dpm = Dp[m];
  size_t idx = ((size_t)(b * LL + l0)) * MM + m;
#pragma unroll 4
  for (int lo = 0; lo < CLEN; ++lo) {
    float dtv = ds_[lo * 64 + ml];
    float xv = xs_[lo * 64 + ml];
    float zv = zs_[lo * 64 + ml];
    float4 Bv = *(const float4*)&bs[lo * 32 + dsub * 4];
    float4 Cv = *(const float4*)&bs[lo * 32 + DD + dsub * 4];
    float dtx = dtv * xv;
    f32x2 dt2; dt2.x = dtv; dt2.y = dtv;
    f32x2 dtx2; dtx2.x = dtx; dtx2.y = dtx;
    f32x2 e01 = pk_mul(dt2, A01), e23 = pk_mul(dt2, A23);
    e01.x = vexp2(e01.x); e01.y = vexp2(e01.y);
    e23.x = vexp2(e23.x); e23.y = vexp2(e23.y);
    f32x2 B01, B23, C01, C23;
    B01.x = Bv.x; B01.y = Bv.y; B23.x = Bv.z; B23.y = Bv.w;
    C01.x = Cv.x; C01.y = Cv.y; C23.x = Cv.z; C23.y = Cv.w;
    h01 = pk_fma(e01, h01, pk_mul(dtx2, B01));
    h23 = pk_fma(e23, h23, pk_mul(dtx2, B23));
    f32x2 ya = pk_mul(h01, C01);
    ya = pk_fma(h23, C23, ya);
    float yp = ya.x + ya.y;
    yp += dpp_xor1(yp);
    yp += dpp_xor2(yp);
    float sig = __builtin_amdgcn_rcpf(1.f + vexp2(-LOG2E * zv));
    if (dsub == 0)
      out[idx + (size_t)lo * MM] = (yp + Dpm * xv) * zv * sig;
  }
}

extern "C" void kernel_launch(void* const* d_in, const int* in_sizes, int n_in,
                              void* d_out, int out_size, void* d_ws, size_t ws_size,
                              hipStream_t stream) {
  const float* x = (const float*)d_in[0];
  const float* z = (const float*)d_in[1];
  const float* W = (const float*)d_in[2];
  const float* dtW = (const float*)d_in[3];
  const float* dtb = (const float*)d_in[4];
  const float* A_log = (const float*)d_in[5];
  const float* Dp = (const float*)d_in[6];
  float* out = (float*)d_out;
  float* ws = (float*)d_ws;

  k_prep<<<224, 256, 0, stream>>>(W, dtW, A_log, ws);
  k_xp<<<(BLROWS / 16) * 3, 64, 0, stream>>>(x, ws);
  k_dt<<<(BLROWS / 16) * 8, 64, 0, stream>>>(dtb, ws);
  k_scan1<<<16 * NCH * BB, 256, 0, stream>>>(x, ws);
  k_scan2<<<128, 256, 0, stream>>>(ws);
  k_scan3<<<16 * NCH * BB, 256, 0, stream>>>(x, z, Dp, out, ws);
}